// Round 6
// baseline (175.624 us; speedup 1.0000x reference)
//
#include <hip/hip_runtime.h>
#include <math.h>

typedef unsigned short ushort_t;
typedef unsigned int uint_t;
typedef unsigned long long u64_t;
typedef __attribute__((ext_vector_type(8))) __bf16 bf16x8;
typedef __attribute__((ext_vector_type(4))) float f32x4;

#define NN 4096
#define TT 5
#define F1 32
#define F2 64

__device__ __forceinline__ ushort_t f2bf(float x) {
    union { float f; uint_t u; } v; v.f = x;
    uint_t r = (v.u + 0x7FFFu + ((v.u >> 16) & 1u)) >> 16;
    return (ushort_t)r;
}
__device__ __forceinline__ float bf16f(float x) {
    union { float f; uint_t u; } v; v.f = x;
    v.u = (v.u + 0x7FFFu + ((v.u >> 16) & 1u)) & 0xFFFF0000u;
    return v.f;
}
__device__ __forceinline__ uint_t pk2(float a, float b) {
    return (uint_t)f2bf(a) | ((uint_t)f2bf(b) << 16);
}
__device__ __forceinline__ float tanh_fast(float x) {
    const float xc = fminf(fmaxf(x, -10.f), 10.f);
    const float e = __expf(2.f * xc);
    return (e - 1.f) * __builtin_amdgcn_rcpf(e + 1.f);
}
// barrier that waits LDS only (lgkmcnt 0) and leaves global loads in flight
__device__ __forceinline__ void lds_barrier() {
    asm volatile("s_waitcnt lgkmcnt(0)\n\ts_barrier" ::: "memory");
}

// ---------------- K1: conv1 (VALU) + conv2 (MFMA); 512 thr, 8 waves, 2 blocks/CU ---------
#define H1S 104
#define CBS 80
__global__ __launch_bounds__(512) void k1_cond(
    const float* __restrict__ ts, const float* __restrict__ Wc1, const float* __restrict__ bc1,
    const float* __restrict__ Wc2, const float* __restrict__ bc2,
    float* __restrict__ condf, ushort_t* __restrict__ condT,
    int* __restrict__ degI, uint_t* __restrict__ colbits)
{
    const int b = blockIdx.y;
    const int j0 = blockIdx.x * 64;
    const int t = threadIdx.x;

    __shared__ float sWc1[384];
    __shared__ float sbc1[F1];
    __shared__ float sbc2[F2];
    __shared__ ushort_t sWc2T[64 * H1S];
    __shared__ ushort_t h1B[64 * H1S];
    __shared__ ushort_t scb[64 * CBS];

    // fold in degI/colbits zeroing (runs before k3 in stream order)
    if (blockIdx.x == 0 && b == 0) {
        for (int i = t; i < 4096; i += 512) degI[i] = 0;
        if (t < 128) colbits[t] = 0u;
    }

    for (int i = t; i < 384; i += 512) sWc1[i] = Wc1[i];
    if (t < F1) sbc1[t] = bc1[t];
    if (t < F2) sbc2[t] = bc2[t];
    for (int i = t; i < 96 * 64; i += 512) {
        const int e = i >> 6, f = i & 63;
        sWc2T[f * H1S + e] = f2bf(Wc2[i]);
    }
    __syncthreads();

    {   // phase A: h1 = relu(conv1); thread -> node (t&63), 12 of 96 entries
        const int n = t & 63, g = t >> 6;
        const int j = j0 + n;
        float4 x[5];
        #pragma unroll
        for (int tt = 0; tt < 5; ++tt)
            x[tt] = *(const float4*)(ts + ((((size_t)b * TT + tt) << 12) + j) * 4);
        #pragma unroll
        for (int q = 0; q < 12; ++q) {
            const int e = g * 12 + q;
            const int tt0 = e >> 5, f1 = e & 31;
            float a = sbc1[f1];
            #pragma unroll
            for (int dt = 0; dt < 3; ++dt) {
                const float4 xx = x[tt0 + dt];
                a += xx.x * sWc1[(dt * 4 + 0) * F1 + f1];
                a += xx.y * sWc1[(dt * 4 + 1) * F1 + f1];
                a += xx.z * sWc1[(dt * 4 + 2) * F1 + f1];
                a += xx.w * sWc1[(dt * 4 + 3) * F1 + f1];
            }
            h1B[n * H1S + e] = f2bf(fmaxf(a, 0.f));
        }
    }
    __syncthreads();

    {   // phase B: cond = h1 @ Wc2 + bc2 via MFMA; wave -> 16 rows x 32 cols
        const int w = t >> 6, l = t & 63;
        const int m0 = (w & 3) * 16, cH = (w >> 2) * 32;
        const int kseg = (l >> 4) * 8;
        f32x4 acc[2] = {};
        #pragma unroll
        for (int ks = 0; ks < 3; ++ks) {
            const bf16x8 av = *(const bf16x8*)&h1B[(m0 + (l & 15)) * H1S + ks * 32 + kseg];
            #pragma unroll
            for (int ct = 0; ct < 2; ++ct) {
                const bf16x8 bv = *(const bf16x8*)&sWc2T[(cH + ct * 16 + (l & 15)) * H1S + ks * 32 + kseg];
                acc[ct] = __builtin_amdgcn_mfma_f32_16x16x32_bf16(av, bv, acc[ct], 0, 0, 0);
            }
        }
        #pragma unroll
        for (int ct = 0; ct < 2; ++ct)
            #pragma unroll
            for (int i = 0; i < 4; ++i) {
                const int row = m0 + (l >> 4) * 4 + i;
                const int col = cH + ct * 16 + (l & 15);
                const float c = acc[ct][i] + sbc2[col];
                condf[((((size_t)b << 12) + j0 + row) << 6) + col] = c;
                scb[col * CBS + row] = f2bf(c);
            }
    }
    __syncthreads();
    {   // condT writeback: 16B/thread
        const int f2 = t >> 3, seg = t & 7;
        ushort_t* dst = condT + (((size_t)b * 64 + f2) << 12) + j0 + seg * 8;
        *(uint4*)dst = *(const uint4*)&scb[f2 * CBS + seg * 8];
    }
}

// ---------------- K3: edges GEMM + deg + colbits; reg-double-buffered B ------------------
__device__ __forceinline__ void stage_chunk(
    const int4 pa, int it, int kq, ushort_t* dstbuf, int soff, uint_t& regm, int& cnt)
{
    const u64_t b0 = __ballot(pa.x != 0);
    const u64_t b1 = __ballot(pa.y != 0);
    const u64_t b2 = __ballot(pa.z != 0);
    const u64_t b3 = __ballot(pa.w != 0);
    const uint_t m0 = (uint_t)(b0 | (b0 >> 32)), m1 = (uint_t)(b1 | (b1 >> 32));
    const uint_t m2 = (uint_t)(b2 | (b2 >> 32)), m3 = (uint_t)(b3 | (b3 >> 32));
    const uint_t nib = ((m0 >> kq) & 1u) | (((m1 >> kq) & 1u) << 1) |
                       (((m2 >> kq) & 1u) << 2) | (((m3 >> kq) & 1u) << 3);
    regm |= nib << (it * 4);
    cnt += (pa.x != 0) + (pa.y != 0) + (pa.z != 0) + (pa.w != 0);
    const uint_t h01 = (pa.x ? 0x3F80u : 0u) | (pa.y ? 0x3F800000u : 0u);
    const uint_t h23 = (pa.z ? 0x3F80u : 0u) | (pa.w ? 0x3F800000u : 0u);
    *(uint2*)(dstbuf + soff) = make_uint2(h01, h23);
}

__global__ __launch_bounds__(1024, 8) void k3_gemm(
    const int* __restrict__ edges, const ushort_t* __restrict__ condT,
    float* __restrict__ agg0, float* __restrict__ agg1,
    float* __restrict__ agg2, float* __restrict__ agg3,
    int* __restrict__ degI, uint_t* __restrict__ colbits)
{
    const int t = threadIdx.x;
    const int stripe = blockIdx.x >> 2, ks4 = blockIdx.x & 3;
    const int j0 = stripe * 32, kb = ks4 * 1024;

    __shared__ __align__(16) ushort_t abuf[8][4096];

    const int w = t >> 6, l = t & 63;
    const int r = t >> 5, kq = t & 31;
    const int rl = r & 15, rh = r >> 4;
    const int ks_s = kq >> 3, q_s = (kq >> 1) & 3;
    const int soff = (rh * 2048 + ks_s * 512 + (q_s * 16 + rl) * 8 + (kq & 1) * 4) ^ (q_s << 4);
    const int aoff = (l * 8) ^ ((l >> 4) << 4);

    const int* ep = edges + (size_t)(j0 + r) * NN + kb + kq * 4;
    const ushort_t* bp = condT + (size_t)(w * 16 + (l & 15)) * NN + kb + (l >> 4) * 8;

    uint_t regm = 0; int cnt = 0;
    int4 pa[4];
    bf16x8 bcur[4], bnxt[4];

    // prologue: edges group-0 loads + B chunk-0 loads all in flight together
    #pragma unroll
    for (int c = 0; c < 4; ++c) pa[c] = *(const int4*)(ep + c * 128);
    #pragma unroll
    for (int ks = 0; ks < 4; ++ks) bcur[ks] = *(const bf16x8*)(bp + ks * 32);
    #pragma unroll
    for (int c = 0; c < 4; ++c) stage_chunk(pa[c], c, kq, &abuf[c][0], soff, regm, cnt);
    lds_barrier();   // LDS-only wait: B loads stay in flight

    // edges group-1 loads fly during compute of group 0
    #pragma unroll
    for (int c = 0; c < 4; ++c) pa[c] = *(const int4*)(ep + (c + 4) * 128);

    f32x4 acc0 = {0.f, 0.f, 0.f, 0.f};
    f32x4 acc1 = {0.f, 0.f, 0.f, 0.f};

    #pragma unroll
    for (int ch = 0; ch < 4; ++ch) {
        // prefetch next chunk's B (ch=3 prefetches chunk 4, across the barrier)
        const ushort_t* bpn = bp + (ch + 1) * 128;
        #pragma unroll
        for (int ks = 0; ks < 4; ++ks) bnxt[ks] = *(const bf16x8*)(bpn + ks * 32);
        const ushort_t* ab = &abuf[ch][0];
        #pragma unroll
        for (int ks = 0; ks < 4; ++ks) {
            const bf16x8 a0 = *(const bf16x8*)(ab + ks * 512 + aoff);
            const bf16x8 a1 = *(const bf16x8*)(ab + 2048 + ks * 512 + aoff);
            acc0 = __builtin_amdgcn_mfma_f32_16x16x32_bf16(a0, bcur[ks], acc0, 0, 0, 0);
            acc1 = __builtin_amdgcn_mfma_f32_16x16x32_bf16(a1, bcur[ks], acc1, 0, 0, 0);
        }
        #pragma unroll
        for (int ks = 0; ks < 4; ++ks) bcur[ks] = bnxt[ks];
    }
    #pragma unroll
    for (int c = 0; c < 4; ++c) stage_chunk(pa[c], c + 4, kq, &abuf[c + 4][0], soff, regm, cnt);
    lds_barrier();   // B chunk-4 loads stay in flight

    #pragma unroll
    for (int ch = 4; ch < 8; ++ch) {
        if (ch < 7) {
            const ushort_t* bpn = bp + (ch + 1) * 128;
            #pragma unroll
            for (int ks = 0; ks < 4; ++ks) bnxt[ks] = *(const bf16x8*)(bpn + ks * 32);
        }
        const ushort_t* ab = &abuf[ch][0];
        #pragma unroll
        for (int ks = 0; ks < 4; ++ks) {
            const bf16x8 a0 = *(const bf16x8*)(ab + ks * 512 + aoff);
            const bf16x8 a1 = *(const bf16x8*)(ab + 2048 + ks * 512 + aoff);
            acc0 = __builtin_amdgcn_mfma_f32_16x16x32_bf16(a0, bcur[ks], acc0, 0, 0, 0);
            acc1 = __builtin_amdgcn_mfma_f32_16x16x32_bf16(a1, bcur[ks], acc1, 0, 0, 0);
        }
        if (ch < 7) {
            #pragma unroll
            for (int ks = 0; ks < 4; ++ks) bcur[ks] = bnxt[ks];
        }
    }

    {   // epilogue: plain stores to this split's slab
        float* aggS = (ks4 == 0) ? agg0 : (ks4 == 1) ? agg1 : (ks4 == 2) ? agg2 : agg3;
        const int col = w * 16 + (l & 15);
        float* dst = aggS + ((size_t)(col >> 6) * NN << 6) + (col & 63);
        #pragma unroll
        for (int i = 0; i < 4; ++i) {
            const int ja = j0 + (l >> 4) * 4 + i;
            dst[(size_t)ja << 6] = acc0[i];
            dst[(size_t)(ja + 16) << 6] = acc1[i];
        }
    }
    {   // deg: shfl-reduce across the 32 lanes sharing a row
        int s = cnt;
        #pragma unroll
        for (int off = 16; off >= 1; off >>= 1) s += __shfl_down(s, off, 32);
        if (kq == 0) atomicAdd(&degI[j0 + r], s);
    }
    __syncthreads();
    uint_t* colsh = (uint_t*)&abuf[0][0];
    if (l < 32) colsh[w * 32 + kq] = regm;
    __syncthreads();
    if (t < 32) {
        uint_t v = 0;
        #pragma unroll
        for (int w2 = 0; w2 < 16; ++w2) v |= colsh[w2 * 32 + t];
        colsh[512 + t] = v;
    }
    __syncthreads();
    if (t < 32) {
        const int it = t >> 2, koct = t & 3;
        uint_t word = 0;
        #pragma unroll
        for (int s2 = 0; s2 < 8; ++s2)
            word |= ((colsh[512 + koct * 8 + s2] >> (it * 4)) & 15u) << (s2 * 4);
        atomicOr(&colbits[(kb >> 5) + t], word);
    }
}

// ---------------- K4: MLP epilogue on MFMA; 512 thr, 8 waves, 2 blocks/CU ----------------
#define WGS 88
#define WDS 136
#define HS  69
__global__ __launch_bounds__(512) void k4_mlp(
    const float* __restrict__ ts, const int* __restrict__ edges,
    const float* __restrict__ condf,
    const float* __restrict__ agg0, const float* __restrict__ agg1,
    const float* __restrict__ agg2, const float* __restrict__ agg3,
    const int* __restrict__ degI, const uint_t* __restrict__ colbits,
    const float* __restrict__ Wg1, const float* __restrict__ bg,
    const float* __restrict__ Wd, const float* __restrict__ bd,
    const float* __restrict__ Wo, const float* __restrict__ bo,
    float* __restrict__ out)
{
    const int b = blockIdx.y;
    const int j0 = blockIdx.x * 64;
    const int t = threadIdx.x;

    __shared__ ushort_t sWg1T[64 * WGS];
    __shared__ ushort_t sWdT[64 * WDS];
    __shared__ ushort_t aggB[64 * WGS];
    __shared__ ushort_t catB[64 * WDS];
    __shared__ float sH[64 * HS];
    __shared__ float sWo[256];
    __shared__ float sbg[64], sbd[64], sbo[4], sAlive[64];

    for (int i = t; i < 4096; i += 512) {
        const int in = i >> 6, o = i & 63;
        sWg1T[o * WGS + in] = f2bf(Wg1[i]);
    }
    for (int i = t; i < 8192; i += 512) {
        const int in = i >> 6, o = i & 63;
        sWdT[o * WDS + in] = f2bf(Wd[i]);
    }
    if (t < 256) sWo[t] = Wo[t];
    if (t >= 256 && t < 320) { sbg[t - 256] = bg[t - 256]; sbd[t - 256] = bd[t - 256]; }
    if (t >= 320 && t < 324) sbo[t - 320] = bo[t - 320];
    if (t >= 384 && t < 448) {
        const int j = j0 + t - 384;
        sAlive[t - 384] = (float)((colbits[j >> 5] >> (j & 31)) & 1u);
    }
    {   // phase 0: aggN = (sum slabs - diag*bf16(cond))/deg -> bf16; cond -> bf16
        const int r = t >> 3, fs = t & 7;
        const int j = j0 + r;
        const float dv = (float)degI[j];
        const float inv = 1.f / (dv > 0.f ? dv : 1.f);
        const float dgf = edges[(size_t)j * NN + j] ? 1.f : 0.f;
        const size_t base = (((size_t)b << 12) + j) << 6;
        #pragma unroll
        for (int q = 0; q < 2; ++q) {
            const int f = fs * 8 + q * 4;
            const float4 a0 = *(const float4*)(agg0 + base + f);
            const float4 a1 = *(const float4*)(agg1 + base + f);
            const float4 a2 = *(const float4*)(agg2 + base + f);
            const float4 a3 = *(const float4*)(agg3 + base + f);
            const float4 c4 = *(const float4*)(condf + base + f);
            const float n0 = (a0.x + a1.x + a2.x + a3.x - dgf * bf16f(c4.x)) * inv;
            const float n1 = (a0.y + a1.y + a2.y + a3.y - dgf * bf16f(c4.y)) * inv;
            const float n2 = (a0.z + a1.z + a2.z + a3.z - dgf * bf16f(c4.z)) * inv;
            const float n3 = (a0.w + a1.w + a2.w + a3.w - dgf * bf16f(c4.w)) * inv;
            *(uint2*)&aggB[r * WGS + f] = make_uint2(pk2(n0, n1), pk2(n2, n3));
            *(uint2*)&catB[r * WDS + f] = make_uint2(pk2(c4.x, c4.y), pk2(c4.z, c4.w));
        }
    }
    __syncthreads();

    const int w = t >> 6, l = t & 63;
    const int m0 = (w & 3) * 16, cH = (w >> 2) * 32;
    const int kseg = (l >> 4) * 8;

    {   // phase G: 16 rows x 32 cols per wave
        f32x4 acc[2] = {};
        #pragma unroll
        for (int ks = 0; ks < 2; ++ks) {
            const bf16x8 av = *(const bf16x8*)&aggB[(m0 + (l & 15)) * WGS + ks * 32 + kseg];
            #pragma unroll
            for (int ct = 0; ct < 2; ++ct) {
                const bf16x8 bv = *(const bf16x8*)&sWg1T[(cH + ct * 16 + (l & 15)) * WGS + ks * 32 + kseg];
                acc[ct] = __builtin_amdgcn_mfma_f32_16x16x32_bf16(av, bv, acc[ct], 0, 0, 0);
            }
        }
        #pragma unroll
        for (int ct = 0; ct < 2; ++ct)
            #pragma unroll
            for (int i = 0; i < 4; ++i) {
                const int row = m0 + (l >> 4) * 4 + i;
                const int col = cH + ct * 16 + (l & 15);
                const float g = tanh_fast(acc[ct][i] + sbg[col]) * sAlive[row];
                catB[row * WDS + 64 + col] = f2bf(g);
            }
    }
    __syncthreads();
    {   // phase H: 16 rows x 32 cols per wave
        f32x4 acc[2] = {};
        #pragma unroll
        for (int ks = 0; ks < 4; ++ks) {
            const bf16x8 av = *(const bf16x8*)&catB[(m0 + (l & 15)) * WDS + ks * 32 + kseg];
            #pragma unroll
            for (int ct = 0; ct < 2; ++ct) {
                const bf16x8 bv = *(const bf16x8*)&sWdT[(cH + ct * 16 + (l & 15)) * WDS + ks * 32 + kseg];
                acc[ct] = __builtin_amdgcn_mfma_f32_16x16x32_bf16(av, bv, acc[ct], 0, 0, 0);
            }
        }
        #pragma unroll
        for (int ct = 0; ct < 2; ++ct)
            #pragma unroll
            for (int i = 0; i < 4; ++i) {
                const int row = m0 + (l >> 4) * 4 + i;
                const int col = cH + ct * 16 + (l & 15);
                sH[row * HS + col] = fmaxf(acc[ct][i] + sbd[col], 0.f);
            }
    }
    __syncthreads();
    if (t < 256) {   // phase O
        const int r = t >> 2, d = t & 3;
        const int j = j0 + r;
        float s = sbo[d];
        #pragma unroll 8
        for (int f = 0; f < 64; ++f) s += sH[r * HS + f] * sWo[f * 4 + d];
        const float segl = ts[((((size_t)b * TT + 4) << 12) + j) * 4 + d];
        out[((((size_t)b << 12) + j) << 2) + d] = segl + tanh_fast(s);
    }
}

// ---------------- launcher ----------------------------------------------------------------
extern "C" void kernel_launch(void* const* d_in, const int* in_sizes, int n_in,
                              void* d_out, int out_size, void* d_ws, size_t ws_size,
                              hipStream_t stream)
{
    (void)in_sizes; (void)n_in; (void)out_size; (void)ws_size;
    const float* ts    = (const float*)d_in[0];
    const int*   edges = (const int*)d_in[1];
    const float* Wc1   = (const float*)d_in[2];
    const float* bc1   = (const float*)d_in[3];
    const float* Wc2   = (const float*)d_in[4];
    const float* bc2   = (const float*)d_in[5];
    const float* Wg1   = (const float*)d_in[6];
    const float* bg    = (const float*)d_in[7];
    const float* Wd    = (const float*)d_in[8];
    const float* bd    = (const float*)d_in[9];
    const float* Wo    = (const float*)d_in[10];
    const float* bo    = (const float*)d_in[11];
    float* out = (float*)d_out;

    char* ws = (char*)d_ws;
    ushort_t* condT   = (ushort_t*)(ws);                        // 2 MiB
    float*    condf   = (float*)(ws + (size_t)(2 << 20));       // 4 MiB
    float*    agg0    = (float*)(ws + (size_t)(6 << 20));       // 4 MiB
    float*    agg1    = (float*)(ws + (size_t)(10 << 20));      // 4 MiB
    float*    agg2    = (float*)(ws + (size_t)(14 << 20));      // 4 MiB
    float*    agg3    = (float*)(ws + (size_t)(18 << 20));      // 4 MiB
    int*      degI    = (int*)(ws + (size_t)(22 << 20));        // 16 KiB
    uint_t*   colbits = (uint_t*)(ws + (size_t)(22 << 20) + 16384); // 512 B

    k1_cond<<<dim3(64, 4), 512, 0, stream>>>(ts, Wc1, bc1, Wc2, bc2, condf, condT,
                                             degI, colbits);
    k3_gemm<<<512, 1024, 0, stream>>>(edges, condT, agg0, agg1, agg2, agg3, degI, colbits);
    k4_mlp<<<dim3(64, 4), 512, 0, stream>>>(ts, edges, condf, agg0, agg1, agg2, agg3,
                                            degI, colbits, Wg1, bg, Wd, bd, Wo, bo, out);
}